// Round 20
// baseline (167.619 us; speedup 1.0000x reference)
//
#include <hip/hip_runtime.h>
#include <hip/hip_fp8.h>

// DynamicConvolution fused pipeline for MI355X (gfx950).
// R20 (base = R19, 132.0; k6 pinned at ~70us across 4 staging variants):
// k6 split into the session's proven shape: kT (streaming transpose, scene
// f32 [c][n] -> St bf16 [n][c], k0_tt's exact tile pattern, 8192 WGs) +
// k5 revived (R15 weff/beff producer) + k6d (kA-shaped: NO LDS, NO barriers
// in the k-loop; af frags from L2-hot weff, bf frags from St rows; 1024 WGs,
// 4 WG/CU). Buffer chain Tt -> P8 -> St reuses one region sequentially.
// Stages: memset -> k0_tt(+weights) -> k23 -> kA -> kB -> kT -> k5 -> k6d.

typedef __attribute__((ext_vector_type(8))) short short8;
typedef __attribute__((ext_vector_type(4))) short short4v;
typedef __attribute__((ext_vector_type(4))) float f32x4;
typedef __attribute__((ext_vector_type(8))) int int8v;

__device__ __forceinline__ unsigned short f2bf(float f){
  unsigned u = __float_as_uint(f);
  u += 0x7FFFu + ((u >> 16) & 1u);           // round-to-nearest-even
  return (unsigned short)(u >> 16);
}
__device__ __forceinline__ unsigned char f2e4m3(float f){
  return __hip_fp8_e4m3(f).__x;              // OCP e4m3 (gfx950 HW format)
}
// monotone float<->uint for atomicMax on floats (incl. negatives)
__device__ __forceinline__ unsigned fenc(float f){
  unsigned u = __float_as_uint(f);
  return (u & 0x80000000u) ? ~u : (u | 0x80000000u);
}
__device__ __forceinline__ float fdec(unsigned k){
  unsigned u = (k & 0x80000000u) ? (k & 0x7FFFFFFFu) : ~k;
  return __uint_as_float(u);
}

// ---------------- k0_tt: Tt[b][n][c] = bf16(T[b][c][n]) + pooled max;
//                  wg>=1024: Wbf[384][256] bf16 (q*0.125 folded) ----------------
__global__ __launch_bounds__(256) void k0_tt(const float* __restrict__ T,
    unsigned short* __restrict__ Tt, unsigned* __restrict__ pooledEnc,
    const float* __restrict__ qw, const float* __restrict__ kw,
    const float* __restrict__ vw, unsigned short* __restrict__ Wbf){
  const int wg = blockIdx.x;
  const int tid = threadIdx.x;
  if (wg >= 1024){                            // weight conversion (96 WGs)
    const int e = ((wg - 1024) * 256 + tid) * 4;
    const int row = e >> 8, c = e & 255;
    const float* src;
    float scl = 1.0f;
    if (row < 64){ src = qw + row * 256 + c; scl = 0.125f; }
    else if (row < 128){ src = kw + (row - 64) * 256 + c; }
    else { src = vw + (row - 128) * 256 + c; }
    float4 v = *(const float4*)src;
    short4v o;
    o[0] = (short)f2bf(v.x * scl); o[1] = (short)f2bf(v.y * scl);
    o[2] = (short)f2bf(v.z * scl); o[3] = (short)f2bf(v.w * scl);
    *(short4v*)(Wbf + e) = o;
    return;
  }
  const int b = wg & 7, nt = (wg >> 3) & 15, ct = wg >> 7;
  const int n0 = nt * 128, c0 = ct * 32;
  __shared__ float Ls[32][129];
  const int cr = tid >> 3, nq = tid & 7;      // 32 c-rows x 8 n-chunks(16 f32)
  const float* src = T + ((size_t)b * 256 + c0 + cr) * 2048 + n0 + nq * 16;
  float4 v0 = ((const float4*)src)[0];
  float4 v1 = ((const float4*)src)[1];
  float4 v2 = ((const float4*)src)[2];
  float4 v3 = ((const float4*)src)[3];
  float mx = fmaxf(fmaxf(fmaxf(v0.x, v0.y), fmaxf(v0.z, v0.w)),
                   fmaxf(fmaxf(v1.x, v1.y), fmaxf(v1.z, v1.w)));
  mx = fmaxf(mx, fmaxf(fmaxf(fmaxf(v2.x, v2.y), fmaxf(v2.z, v2.w)),
                       fmaxf(fmaxf(v3.x, v3.y), fmaxf(v3.z, v3.w))));
  mx = fmaxf(mx, __shfl_xor(mx, 1));
  mx = fmaxf(mx, __shfl_xor(mx, 2));
  mx = fmaxf(mx, __shfl_xor(mx, 4));
  if (nq == 0) atomicMax(&pooledEnc[b * 256 + c0 + cr], fenc(mx));
  float* lr = &Ls[cr][nq * 16];
  *(float4*)lr = v0; *(float4*)(lr + 4) = v1;
  *(float4*)(lr + 8) = v2; *(float4*)(lr + 12) = v3;
  __syncthreads();
  const int nr = tid >> 1, ch = tid & 1;      // 128 n-rows x 2 c-halves(16)
  unsigned short ob[16];
  #pragma unroll
  for (int j = 0; j < 16; j++) ob[j] = f2bf(Ls[ch * 16 + j][nr]);
  unsigned short* dst = Tt + ((size_t)b * 2048 + n0 + nr) * 256 + c0 + ch * 16;
  *(short8*)dst = *(short8*)&ob[0];
  *(short8*)(dst + 8) = *(short8*)&ob[8];
}

// ---------------- kT: St[b][n][c] = bf16(S[b][c][n]) — streaming transpose -------
// 8192 WGs: b = wg&7, nt = (wg>>3)&127 -> 128 n, ct = wg>>10 -> 32 c.
// Exact k0_tt tile pattern (coalesced f32x4 reads, LDS f32 transpose,
// coalesced 16B bf16 writes).
__global__ __launch_bounds__(256) void kT_scene(const float* __restrict__ S,
    unsigned short* __restrict__ St){
  const int wg = blockIdx.x;
  const int b = wg & 7, nt = (wg >> 3) & 127, ct = wg >> 10;
  const int n0 = nt * 128, c0 = ct * 32;
  const int tid = threadIdx.x;
  __shared__ float Ls[32][129];
  const int cr = tid >> 3, nq = tid & 7;      // 32 c-rows x 8 n-chunks(16 f32)
  const float* src = S + ((size_t)b * 256 + c0 + cr) * 16384 + n0 + nq * 16;
  float4 v0 = ((const float4*)src)[0];
  float4 v1 = ((const float4*)src)[1];
  float4 v2 = ((const float4*)src)[2];
  float4 v3 = ((const float4*)src)[3];
  float* lr = &Ls[cr][nq * 16];
  *(float4*)lr = v0; *(float4*)(lr + 4) = v1;
  *(float4*)(lr + 8) = v2; *(float4*)(lr + 12) = v3;
  __syncthreads();
  const int nr = tid >> 1, ch = tid & 1;      // 128 n-rows x 2 c-halves(16)
  unsigned short ob[16];
  #pragma unroll
  for (int j = 0; j < 16; j++) ob[j] = f2bf(Ls[ch * 16 + j][nr]);
  unsigned short* dst = St + ((size_t)b * 16384 + n0 + nr) * 256 + c0 + ch * 16;
  *(short8*)dst = *(short8*)&ob[0];
  *(short8*)(dst + 8) = *(short8*)&ob[8];
}

// ---------------- k23: fused k2 (QKV gemm, wg<512) + k3 (params gemv) ------------
__global__ __launch_bounds__(256) void k23_qkv_params(
    const unsigned short* __restrict__ Wbf, const unsigned short* __restrict__ Tt,
    unsigned short* __restrict__ qo, unsigned short* __restrict__ ko,
    unsigned char* __restrict__ vt8,
    const unsigned* __restrict__ pooledEnc, const float* __restrict__ cw,
    const float* __restrict__ cb, float* __restrict__ params){
  const int wg = blockIdx.x;
  const int tid = threadIdx.x, lane = tid & 63, w = tid >> 6;
  if (wg >= 512){
    __shared__ float P[8 * 256];
    for (int i = tid; i < 2048; i += 256) P[i] = fdec(pooledEnc[i]);
    __syncthreads();
    const int r = (wg - 512) * 4 + w;
    if (r >= 8385) return;
    float4 c4 = ((const float4*)(cw + (size_t)r * 256))[lane];
    float bias = cb[r];
    #pragma unroll
    for (int b = 0; b < 8; b++){
      const float* pbp = P + b * 256 + lane * 4;
      float s = c4.x * pbp[0] + c4.y * pbp[1] + c4.z * pbp[2] + c4.w * pbp[3];
      #pragma unroll
      for (int d = 1; d < 64; d <<= 1) s += __shfl_xor(s, d);
      if (lane == 0) params[b * 8385 + r] = s + bias;
    }
    return;
  }
  const int b = wg & 7, nt = wg >> 3;
  const int n0 = nt * 32;
  const int l15 = lane & 15, g = lane >> 4;
  const unsigned short* Tb = Tt + (size_t)b * 2048 * 256;

  f32x4 aqk[2][2], av[4][2];
  #pragma unroll
  for (int i = 0; i < 2; i++)
    #pragma unroll
    for (int nf = 0; nf < 2; nf++) aqk[i][nf] = (f32x4){0.f,0.f,0.f,0.f};
  #pragma unroll
  for (int j = 0; j < 4; j++)
    #pragma unroll
    for (int nf = 0; nf < 2; nf++) av[j][nf] = (f32x4){0.f,0.f,0.f,0.f};

  #pragma unroll 2
  for (int kc = 0; kc < 8; kc++){
    short8 bfr[2];
    #pragma unroll
    for (int nf = 0; nf < 2; nf++)
      bfr[nf] = *(const short8*)(Tb + (size_t)(n0 + nf * 16 + l15) * 256 + kc * 32 + g * 8);
    short8 aq[2];
    #pragma unroll
    for (int i = 0; i < 2; i++)
      aq[i] = *(const short8*)(Wbf + (size_t)((2 * w + i) * 16 + l15) * 256 + kc * 32 + g * 8);
    short8 afv[4];
    #pragma unroll
    for (int j = 0; j < 4; j++)
      afv[j] = *(const short8*)(Wbf + (size_t)(128 + (4 * w + j) * 16 + l15) * 256 + kc * 32 + g * 8);
    #pragma unroll
    for (int i = 0; i < 2; i++)
      #pragma unroll
      for (int nf = 0; nf < 2; nf++)
        aqk[i][nf] = __builtin_amdgcn_mfma_f32_16x16x32_bf16(aq[i], bfr[nf], aqk[i][nf], 0, 0, 0);
    #pragma unroll
    for (int j = 0; j < 4; j++)
      #pragma unroll
      for (int nf = 0; nf < 2; nf++)
        av[j][nf] = __builtin_amdgcn_mfma_f32_16x16x32_bf16(bfr[nf], afv[j], av[j][nf], 0, 0, 0);
  }
  unsigned short* qk = (w < 2) ? qo : ko;
  #pragma unroll
  for (int i = 0; i < 2; i++)
    #pragma unroll
    for (int nf = 0; nf < 2; nf++){
      int n = n0 + nf * 16 + l15;
      int cbase = (w & 1) * 32 + i * 16 + g * 4;
      short4v pk;
      #pragma unroll
      for (int r = 0; r < 4; r++) pk[r] = (short)f2bf(aqk[i][nf][r]);
      *(short4v*)(qk + ((size_t)b * 2048 + n) * 64 + cbase) = pk;
    }
  #pragma unroll
  for (int j = 0; j < 4; j++)
    #pragma unroll
    for (int nf = 0; nf < 2; nf++){
      int o = (4 * w + j) * 16 + l15;
      int nb2 = n0 + nf * 16 + g * 4;
      unsigned pv8 = 0;
      #pragma unroll
      for (int r = 0; r < 4; r++)
        pv8 |= (unsigned)f2e4m3(av[j][nf][r]) << (8 * r);
      *(unsigned*)(vt8 + ((size_t)b * 256 + o) * 2048 + nb2) = pv8;
    }
}

// ---------------- kA v5: swapped QK -> P fp8 row-major [q][2048] -----------------
__global__ __launch_bounds__(512, 4) void kA_scores(
    const unsigned short* __restrict__ Qg, const unsigned short* __restrict__ Kg,
    unsigned char* __restrict__ Pg, float* __restrict__ sbuf,
    int b0, int bshift){
  const int wg = blockIdx.x;
  const int bmask = (1 << bshift) - 1;
  const int b = b0 + (wg & bmask);
  const int q0 = (wg >> bshift) * 32;
  const int tid = threadIdx.x, lane = tid & 63, w = tid >> 6;
  const int l15 = lane & 15, g = lane >> 4;
  __shared__ float wsum[32][8];
  const unsigned short* Qb = Qg + (size_t)b * 2048 * 64;
  const unsigned short* Kb = Kg + (size_t)b * 2048 * 64;
  unsigned char* Pb = Pg + (size_t)(wg & bmask) * 2048 * 2048;

  short8 qf[2][2];
  #pragma unroll
  for (int qi = 0; qi < 2; qi++)
    #pragma unroll
    for (int kc = 0; kc < 2; kc++)
      qf[qi][kc] = *(const short8*)(Qb + (size_t)(q0 + qi * 16 + l15) * 64 + kc * 32 + g * 8);

  float ps[2] = {0.f, 0.f};                   // per-lane partial for q = qi*16+l15

  const int wm0 = w * 256;
  #pragma unroll
  for (int mt = 0; mt < 4; ++mt){
    const int mb = wm0 + mt * 64;
    short8 kf[4][2];
    #pragma unroll
    for (int mi = 0; mi < 4; mi++)
      #pragma unroll
      for (int kc = 0; kc < 2; kc++)
        kf[mi][kc] = *(const short8*)(Kb + (size_t)(mb + mi * 16 + l15) * 64 + kc * 32 + g * 8);
    #pragma unroll
    for (int qi = 0; qi < 2; qi++){
      f32x4 sa[4];
      #pragma unroll
      for (int mi = 0; mi < 4; mi++) sa[mi] = (f32x4){0.f,0.f,0.f,0.f};
      #pragma unroll
      for (int mi = 0; mi < 4; mi++)
        #pragma unroll
        for (int kc = 0; kc < 2; kc++)
          sa[mi] = __builtin_amdgcn_mfma_f32_16x16x32_bf16(kf[mi][kc], qf[qi][kc], sa[mi], 0, 0, 0);
      #pragma unroll
      for (int mi = 0; mi < 4; mi++){
        unsigned pk8 = 0;
        #pragma unroll
        for (int r = 0; r < 4; r++){
          float p = __expf(sa[mi][r]);        // sa[mi][r] = S[m=mb+mi*16+g*4+r][q]
          ps[qi] += p;
          pk8 |= (unsigned)f2e4m3(p) << (8 * r);
        }
        *(unsigned*)(Pb + (size_t)(q0 + qi * 16 + l15) * 2048 + mb + mi * 16 + g * 4) = pk8;
      }
    }
  }
  #pragma unroll
  for (int qi = 0; qi < 2; qi++){
    float t = ps[qi];
    t += __shfl_xor(t, 16);
    t += __shfl_xor(t, 32);                   // sum over the 4 g-groups
    if (lane < 16) wsum[qi * 16 + l15][w] = t;
  }
  __syncthreads();
  if (tid < 32){
    float t = 0.f;
    #pragma unroll
    for (int i = 0; i < 8; i++) t += wsum[tid][i];
    sbuf[(size_t)b * 2048 + q0 + tid] = t;
  }
}

// ---------------- kB v7: O = P8@V8^T via MX-scaled fp8 MFMA (K=128) --------------
__global__ __launch_bounds__(256, 3) void kB_pv(
    const unsigned char* __restrict__ Pg, const unsigned char* __restrict__ Vt,
    const float* __restrict__ sbuf, unsigned* __restrict__ tmaxe,
    int b0, int bshift){
  const int wg = blockIdx.x;
  const int bmask = (1 << bshift) - 1;
  const int b = b0 + (wg & bmask);
  const int rest = wg >> bshift;
  const int oh = rest & 1;
  const int n0 = (rest >> 1) * 64;
  const int tid = threadIdx.x, lane = tid & 63, w = tid >> 6;
  const int l15 = lane & 15, g = lane >> 4;
  __shared__ __align__(32) unsigned char smem[2][24576];  // dbuf: Pl 8KB | Vl 16KB

  const unsigned char* Pb = Pg + (size_t)(wg & bmask) * 2048 * 2048;
  const unsigned char* Vb = Vt + ((size_t)b * 256 + oh * 128) * 2048;

  f32x4 acc[4][2];
  #pragma unroll
  for (int ni = 0; ni < 4; ni++)
    #pragma unroll
    for (int oi = 0; oi < 2; oi++) acc[ni][oi] = (f32x4){0.f,0.f,0.f,0.f};

  const unsigned char* psrc[6];
  {
    #pragma unroll
    for (int k = 0; k < 6; k++){
      int d = k * 4096 + w * 1024 + lane * 16;
      if (k < 2){                                        // P: 64 rows x 128B
        int row = d >> 7;
        int colB = (d & 127) ^ ((row & 3) << 5);
        psrc[k] = Pb + (size_t)(n0 + row) * 2048 + colB;
      } else {                                           // V-half: 128 rows x 128B
        int dv = d - 8192;
        int row = dv >> 7;
        int colB = (dv & 127) ^ ((row & 3) << 5);
        psrc[k] = Vb + (size_t)row * 2048 + colB;
      }
    }
  }
  auto ISSUE = [&](int m0, int bufIdx){
    #pragma unroll
    for (int k = 0; k < 6; k++){
      unsigned char* dst = &smem[bufIdx][k * 4096 + w * 1024];  // wave-uniform
      __builtin_amdgcn_global_load_lds(
          (const __attribute__((address_space(1))) void*)(psrc[k] + m0),
          (__attribute__((address_space(3))) void*)dst, 16, 0, 0);
    }
  };

  ISSUE(0, 0);
  __syncthreads();                                     // drains vmcnt: buf0 ready

  const int SC = 0x7F7F7F7F;                           // E8M0 1.0 per block
  for (int t = 0; t < 16; ++t){
    unsigned char* cur = smem[t & 1];
    if (t < 15) ISSUE((t + 1) * 128, (t + 1) & 1);     // async into other buffer
    int8v af[4], bf[2];
    #pragma unroll
    for (int ni = 0; ni < 4; ni++){
      int row = ni * 16 + l15;
      af[ni] = *(const int8v*)(cur + row * 128 + ((g * 32) ^ ((row & 3) << 5)));
    }
    #pragma unroll
    for (int oi = 0; oi < 2; oi++){
      int row = w * 32 + oi * 16 + l15;
      bf[oi] = *(const int8v*)(cur + 8192 + row * 128 + ((g * 32) ^ ((row & 3) << 5)));
    }
    #pragma unroll
    for (int ni = 0; ni < 4; ni++)
      #pragma unroll
      for (int oi = 0; oi < 2; oi++)
        acc[ni][oi] = __builtin_amdgcn_mfma_scale_f32_16x16x128_f8f6f4(
            af[ni], bf[oi], acc[ni][oi], 0, 0, 0, SC, 0, SC);
    if (t < 15)
      __syncthreads();                                 // next buf ready; cur reads done
  }
  float inv[4][4];
  #pragma unroll
  for (int ni = 0; ni < 4; ni++)
    #pragma unroll
    for (int r = 0; r < 4; r++)
      inv[ni][r] = 1.0f / sbuf[(size_t)b * 2048 + n0 + ni * 16 + g * 4 + r];
  #pragma unroll
  for (int oi = 0; oi < 2; oi++){
    float cm = -1e30f;
    #pragma unroll
    for (int ni = 0; ni < 4; ni++)
      #pragma unroll
      for (int r = 0; r < 4; r++)
        cm = fmaxf(cm, acc[ni][oi][r] * inv[ni][r]);
    cm = fmaxf(cm, __shfl_xor(cm, 16));
    cm = fmaxf(cm, __shfl_xor(cm, 32));
    if (lane < 16)
      atomicMax(&tmaxe[b * 256 + oh * 128 + w * 32 + oi * 16 + lane], fenc(cm));
  }
}

// ---------------- k5 (revived, R15 form minus w0b/w1b): weff bf16 + beff ---------
__global__ __launch_bounds__(256) void k5_weff(const float* __restrict__ proj_w,
    const float* __restrict__ proj_b, const unsigned* __restrict__ tmaxe,
    unsigned short* __restrict__ weff, float* __restrict__ beff){
  const int b = blockIdx.y, o = blockIdx.x;
  const int c = threadIdx.x;                  // 256
  float t = fdec(tmaxe[b * 256 + c]);
  float p0 = proj_w[o * 768 + c];
  float p1 = proj_w[o * 768 + 256 + c];
  float p2 = proj_w[o * 768 + 512 + c];
  weff[((size_t)b * 64 + o) * 256 + c] = f2bf(p0 + p1 * t + p2);
  float s = p0 * t;
  #pragma unroll
  for (int d = 1; d < 64; d <<= 1) s += __shfl_xor(s, d);
  __shared__ float sm[4];
  if ((c & 63) == 0) sm[c >> 6] = s;
  __syncthreads();
  if (c == 0) beff[b * 64 + o] = proj_b[o] - (sm[0] + sm[1] + sm[2] + sm[3]);
}

// ---------------- k6d: scene MLP, kA-shaped — NO LDS / NO barriers in loop -------
// 1024 WGs (b = wg&7, nt = wg>>3 -> 128 n), 256 thr / 4 waves; wave owns 32 n.
// Loop kc: af from weff global (L2-hot), bf from St rows (direct 16B frags),
// 8 MFMA. LDS only for H0/H1 (16KB each) in the layer epilogue.
__global__ __launch_bounds__(256) void k6_main(const unsigned short* __restrict__ St,
    const unsigned short* __restrict__ weff, const float* __restrict__ beff,
    const float* __restrict__ params, float* __restrict__ out){
  const int wg = blockIdx.x;
  const int b = wg & 7, nt = wg >> 3;
  const int n0 = nt * 128;
  const int tid = threadIdx.x, lane = tid & 63, w = tid >> 6;
  const int l15 = lane & 15, g = lane >> 4;
  __shared__ __align__(16) unsigned char smem[32768];
  unsigned short* H0 = (unsigned short*)smem;            // [128 n][64 o] 16KB
  unsigned short* H1 = (unsigned short*)(smem + 16384);  // 16KB

  const unsigned short* Stb = St + ((size_t)b * 16384 + n0) * 256;
  const unsigned short* We = weff + (size_t)b * 64 * 256;
  f32x4 a0[4][2];
  #pragma unroll
  for (int mi = 0; mi < 4; mi++)
    #pragma unroll
    for (int ni = 0; ni < 2; ni++) a0[mi][ni] = (f32x4){0.f,0.f,0.f,0.f};

  #pragma unroll
  for (int kc = 0; kc < 8; kc++){
    short8 bf0[2];
    #pragma unroll
    for (int ni = 0; ni < 2; ni++){
      int n = w * 32 + ni * 16 + l15;
      bf0[ni] = *(const short8*)(Stb + (size_t)n * 256 + kc * 32 + g * 8);
    }
    #pragma unroll
    for (int mi = 0; mi < 4; mi++){
      short8 af = *(const short8*)(We + (size_t)(mi * 16 + l15) * 256 + kc * 32 + g * 8);
      #pragma unroll
      for (int ni = 0; ni < 2; ni++)
        a0[mi][ni] = __builtin_amdgcn_mfma_f32_16x16x32_bf16(af, bf0[ni], a0[mi][ni], 0, 0, 0);
    }
  }
  // layer0 epilogue: relu(+beff) -> H0
  const float* be = beff + b * 64;
  #pragma unroll
  for (int mi = 0; mi < 4; mi++)
    #pragma unroll
    for (int ni = 0; ni < 2; ni++){
      int n = w * 32 + ni * 16 + l15;
      unsigned base = ((unsigned)(n * 128 + mi * 32 + g * 8)) ^ ((unsigned)((n & 7) << 4));
      unsigned short hh[4];
      #pragma unroll
      for (int r = 0; r < 4; r++){
        int o = mi * 16 + g * 4 + r;
        hh[r] = f2bf(fmaxf(a0[mi][ni][r] + be[o], 0.f));
      }
      *(unsigned*)((unsigned char*)H0 + base)     = (unsigned)hh[0] | ((unsigned)hh[1] << 16);
      *(unsigned*)((unsigned char*)H0 + base + 4) = (unsigned)hh[2] | ((unsigned)hh[3] << 16);
    }
  __syncthreads();
  const float* pp = params + (size_t)b * 8385;
  // layer1: w0 from params f32, converted inline
  f32x4 a1[4][2];
  #pragma unroll
  for (int mi = 0; mi < 4; mi++)
    #pragma unroll
    for (int ni = 0; ni < 2; ni++) a1[mi][ni] = (f32x4){0.f,0.f,0.f,0.f};
  #pragma unroll
  for (int ks = 0; ks < 2; ks++){
    short8 bfh[2];
    #pragma unroll
    for (int ni = 0; ni < 2; ni++){
      int n = w * 32 + ni * 16 + l15;
      unsigned off = ((unsigned)(n * 128 + ks * 64 + g * 16)) ^ ((unsigned)((n & 7) << 4));
      bfh[ni] = *(const short8*)((unsigned char*)H0 + off);
    }
    #pragma unroll
    for (int mi = 0; mi < 4; mi++){
      const float* wsrc = pp + (mi * 16 + l15) * 64 + ks * 32 + g * 8;
      float4 x0 = *(const float4*)wsrc;
      float4 x1 = *(const float4*)(wsrc + 4);
      short8 af;
      af[0] = (short)f2bf(x0.x); af[1] = (short)f2bf(x0.y);
      af[2] = (short)f2bf(x0.z); af[3] = (short)f2bf(x0.w);
      af[4] = (short)f2bf(x1.x); af[5] = (short)f2bf(x1.y);
      af[6] = (short)f2bf(x1.z); af[7] = (short)f2bf(x1.w);
      #pragma unroll
      for (int ni = 0; ni < 2; ni++)
        a1[mi][ni] = __builtin_amdgcn_mfma_f32_16x16x32_bf16(af, bfh[ni], a1[mi][ni], 0, 0, 0);
    }
  }
  const float* b0p = pp + 8256;
  #pragma unroll
  for (int mi = 0; mi < 4; mi++)
    #pragma unroll
    for (int ni = 0; ni < 2; ni++){
      int n = w * 32 + ni * 16 + l15;
      unsigned base = ((unsigned)(n * 128 + mi * 32 + g * 8)) ^ ((unsigned)((n & 7) << 4));
      unsigned short hh[4];
      #pragma unroll
      for (int r = 0; r < 4; r++){
        int o = mi * 16 + g * 4 + r;
        hh[r] = f2bf(fmaxf(a1[mi][ni][r] + b0p[o], 0.f));
      }
      *(unsigned*)((unsigned char*)H1 + base)     = (unsigned)hh[0] | ((unsigned)hh[1] << 16);
      *(unsigned*)((unsigned char*)H1 + base + 4) = (unsigned)hh[2] | ((unsigned)hh[3] << 16);
    }
  __syncthreads();
  // layer2: w1 from params f32, converted inline; fused w2 dot + b2
  f32x4 a2[4][2];
  #pragma unroll
  for (int mi = 0; mi < 4; mi++)
    #pragma unroll
    for (int ni = 0; ni < 2; ni++) a2[mi][ni] = (f32x4){0.f,0.f,0.f,0.f};
  #pragma unroll
  for (int ks = 0; ks < 2; ks++){
    short8 bfh[2];
    #pragma unroll
    for (int ni = 0; ni < 2; ni++){
      int n = w * 32 + ni * 16 + l15;
      unsigned off = ((unsigned)(n * 128 + ks * 64 + g * 16)) ^ ((unsigned)((n & 7) << 4));
      bfh[ni] = *(const short8*)((unsigned char*)H1 + off);
    }
    #pragma unroll
    for (int mi = 0; mi < 4; mi++){
      const float* wsrc = pp + 4096 + (mi * 16 + l15) * 64 + ks * 32 + g * 8;
      float4 x0 = *(const float4*)wsrc;
      float4 x1 = *(const float4*)(wsrc + 4);
      short8 af;
      af[0] = (short)f2bf(x0.x); af[1] = (short)f2bf(x0.y);
      af[2] = (short)f2bf(x0.z); af[3] = (short)f2bf(x0.w);
      af[4] = (short)f2bf(x1.x); af[5] = (short)f2bf(x1.y);
      af[6] = (short)f2bf(x1.z); af[7] = (short)f2bf(x1.w);
      #pragma unroll
      for (int ni = 0; ni < 2; ni++)
        a2[mi][ni] = __builtin_amdgcn_mfma_f32_16x16x32_bf16(af, bfh[ni], a2[mi][ni], 0, 0, 0);
    }
  }
  const float* b1p = pp + 8320;
  const float* w2p = pp + 8192;
  float b2v = pp[8384];
  #pragma unroll
  for (int ni = 0; ni < 2; ni++){
    float t = 0.f;
    #pragma unroll
    for (int mi = 0; mi < 4; mi++)
      #pragma unroll
      for (int r = 0; r < 4; r++){
        int o = mi * 16 + g * 4 + r;
        t += w2p[o] * fmaxf(a2[mi][ni][r] + b1p[o], 0.f);
      }
    t += __shfl_xor(t, 16);
    t += __shfl_xor(t, 32);
    if (lane < 16)
      out[(size_t)b * 16384 + n0 + w * 32 + ni * 16 + l15] = t + b2v;
  }
}

extern "C" void kernel_launch(void* const* d_in, const int* in_sizes, int n_in,
                              void* d_out, int out_size, void* d_ws, size_t ws_size,
                              hipStream_t stream){
  const float* scene = (const float*)d_in[0];
  const float* tmpl  = (const float*)d_in[1];
  const float* qw    = (const float*)d_in[2];
  const float* kw    = (const float*)d_in[3];
  const float* vw    = (const float*)d_in[4];
  const float* pw    = (const float*)d_in[5];
  const float* pb    = (const float*)d_in[6];
  const float* cw    = (const float*)d_in[7];
  const float* cb    = (const float*)d_in[8];
  float* out = (float*)d_out;
  char* ws = (char*)d_ws;

  unsigned short* Q      = (unsigned short*)(ws + 0);                    // 2 MB
  unsigned short* K      = (unsigned short*)(ws + (2u << 20));           // 2 MB
  unsigned char*  V8     = (unsigned char*)(ws + (4u << 20));            // 4 MB
  unsigned*       pooledEnc = (unsigned*)(ws + (12u << 20));             // 8 KB
  unsigned*       tmaxe  = (unsigned*)(ws + (12u << 20) + 8192);         // 8 KB
  float*          params = (float*)(ws + (12u << 20) + 16384);           // 268 KB
  unsigned short* weff   = (unsigned short*)(ws + (13u << 20));          // 256 KB
  float*          beff   = (float*)(ws + (13u << 20) + 262144);          // 2 KB
  float*          sbuf   = (float*)(ws + (14u << 20));                   // 64 KB
  unsigned short* Wbf    = (unsigned short*)(ws + (14u << 20) + 131072); // 192 KB
  unsigned char*  P8buf  = (unsigned char*)(ws + (16u << 20));           // 33.5 MB max
  unsigned short* Tt     = (unsigned short*)P8buf;  // 8 MB; dead before kA writes
  unsigned short* St     = (unsigned short*)P8buf;  // 67 MB; written after kB (P8 dead)

  const size_t pPerBatch = (size_t)2048 * 2048;     // 4 MB fp8 per batch
  size_t avail = ws_size > (16u << 20) ? ws_size - (16u << 20) : 0;
  int nb = 8, bshift = 3;
  while (nb > 1 && (size_t)nb * pPerBatch > avail){ nb >>= 1; bshift--; }

  hipMemsetAsync(ws + (12u << 20), 0, 16384, stream);   // pooledEnc + tmaxe floors
  k0_tt<<<dim3(1120), dim3(256), 0, stream>>>(tmpl, Tt, pooledEnc, qw, kw, vw, Wbf);
  k23_qkv_params<<<dim3(512 + 2097), dim3(256), 0, stream>>>(Wbf, Tt, Q, K, V8,
                                                             pooledEnc, cw, cb, params);
  for (int b0 = 0; b0 < 8; b0 += nb){
    kA_scores<<<dim3(64 * nb), dim3(512), 0, stream>>>(Q, K, P8buf, sbuf, b0, bshift);
    kB_pv<<<dim3(64 * nb), dim3(256), 0, stream>>>(P8buf, V8, sbuf, tmaxe, b0, bshift);
  }
  kT_scene<<<dim3(8192), dim3(256), 0, stream>>>(scene, St);
  k5_weff<<<dim3(64, 8), dim3(256), 0, stream>>>(pw, pb, tmaxe, weff, beff);
  k6_main<<<dim3(1024), dim3(256), 0, stream>>>(St, weff, beff, params, out);
}

// Round 21
// 130.781 us; speedup vs baseline: 1.2817x; 1.2817x over previous
//
#include <hip/hip_runtime.h>
#include <hip/hip_fp8.h>

// DynamicConvolution fused pipeline for MI355X (gfx950).
// R21 = R15 (best, 130.7) wholesale + ONE change: k6 n-tile 256->128
// (256 thr, 1024 WGs, 32KB LDS -> 5 WG/CU, 2.5x in-flight scene loads).
// Scene bytes read exactly once regardless of tile => no reuse amplification.
// Stages: memset -> k0_tt(+weights) -> k23 qkv+params -> kA exp(QK^T) ->
//         kB PV+tmax (MX fp8) -> k5 W_eff -> k6 fused scene MLP.

typedef __attribute__((ext_vector_type(8))) short short8;
typedef __attribute__((ext_vector_type(4))) short short4v;
typedef __attribute__((ext_vector_type(4))) float f32x4;
typedef __attribute__((ext_vector_type(8))) int int8v;

__device__ __forceinline__ unsigned short f2bf(float f){
  unsigned u = __float_as_uint(f);
  u += 0x7FFFu + ((u >> 16) & 1u);           // round-to-nearest-even
  return (unsigned short)(u >> 16);
}
__device__ __forceinline__ unsigned char f2e4m3(float f){
  return __hip_fp8_e4m3(f).__x;              // OCP e4m3 (gfx950 HW format)
}
// monotone float<->uint for atomicMax on floats (incl. negatives)
__device__ __forceinline__ unsigned fenc(float f){
  unsigned u = __float_as_uint(f);
  return (u & 0x80000000u) ? ~u : (u | 0x80000000u);
}
__device__ __forceinline__ float fdec(unsigned k){
  unsigned u = (k & 0x80000000u) ? (k & 0x7FFFFFFFu) : ~k;
  return __uint_as_float(u);
}

// ---------------- k0_tt: Tt[b][n][c] = bf16(T[b][c][n]) + pooled max;
//                  wg>=1024: Wbf[384][256] bf16 (q*0.125 folded) ----------------
__global__ __launch_bounds__(256) void k0_tt(const float* __restrict__ T,
    unsigned short* __restrict__ Tt, unsigned* __restrict__ pooledEnc,
    const float* __restrict__ qw, const float* __restrict__ kw,
    const float* __restrict__ vw, unsigned short* __restrict__ Wbf){
  const int wg = blockIdx.x;
  const int tid = threadIdx.x;
  if (wg >= 1024){                            // weight conversion (96 WGs)
    const int e = ((wg - 1024) * 256 + tid) * 4;
    const int row = e >> 8, c = e & 255;
    const float* src;
    float scl = 1.0f;
    if (row < 64){ src = qw + row * 256 + c; scl = 0.125f; }
    else if (row < 128){ src = kw + (row - 64) * 256 + c; }
    else { src = vw + (row - 128) * 256 + c; }
    float4 v = *(const float4*)src;
    short4v o;
    o[0] = (short)f2bf(v.x * scl); o[1] = (short)f2bf(v.y * scl);
    o[2] = (short)f2bf(v.z * scl); o[3] = (short)f2bf(v.w * scl);
    *(short4v*)(Wbf + e) = o;
    return;
  }
  const int b = wg & 7, nt = (wg >> 3) & 15, ct = wg >> 7;
  const int n0 = nt * 128, c0 = ct * 32;
  __shared__ float Ls[32][129];
  const int cr = tid >> 3, nq = tid & 7;      // 32 c-rows x 8 n-chunks(16 f32)
  const float* src = T + ((size_t)b * 256 + c0 + cr) * 2048 + n0 + nq * 16;
  float4 v0 = ((const float4*)src)[0];
  float4 v1 = ((const float4*)src)[1];
  float4 v2 = ((const float4*)src)[2];
  float4 v3 = ((const float4*)src)[3];
  float mx = fmaxf(fmaxf(fmaxf(v0.x, v0.y), fmaxf(v0.z, v0.w)),
                   fmaxf(fmaxf(v1.x, v1.y), fmaxf(v1.z, v1.w)));
  mx = fmaxf(mx, fmaxf(fmaxf(fmaxf(v2.x, v2.y), fmaxf(v2.z, v2.w)),
                       fmaxf(fmaxf(v3.x, v3.y), fmaxf(v3.z, v3.w))));
  mx = fmaxf(mx, __shfl_xor(mx, 1));
  mx = fmaxf(mx, __shfl_xor(mx, 2));
  mx = fmaxf(mx, __shfl_xor(mx, 4));
  if (nq == 0) atomicMax(&pooledEnc[b * 256 + c0 + cr], fenc(mx));
  float* lr = &Ls[cr][nq * 16];
  *(float4*)lr = v0; *(float4*)(lr + 4) = v1;
  *(float4*)(lr + 8) = v2; *(float4*)(lr + 12) = v3;
  __syncthreads();
  const int nr = tid >> 1, ch = tid & 1;      // 128 n-rows x 2 c-halves(16)
  unsigned short ob[16];
  #pragma unroll
  for (int j = 0; j < 16; j++) ob[j] = f2bf(Ls[ch * 16 + j][nr]);
  unsigned short* dst = Tt + ((size_t)b * 2048 + n0 + nr) * 256 + c0 + ch * 16;
  *(short8*)dst = *(short8*)&ob[0];
  *(short8*)(dst + 8) = *(short8*)&ob[8];
}

// ---------------- k23: fused k2 (QKV gemm, wg<512) + k3 (params gemv) ------------
__global__ __launch_bounds__(256) void k23_qkv_params(
    const unsigned short* __restrict__ Wbf, const unsigned short* __restrict__ Tt,
    unsigned short* __restrict__ qo, unsigned short* __restrict__ ko,
    unsigned char* __restrict__ vt8,
    const unsigned* __restrict__ pooledEnc, const float* __restrict__ cw,
    const float* __restrict__ cb, float* __restrict__ params){
  const int wg = blockIdx.x;
  const int tid = threadIdx.x, lane = tid & 63, w = tid >> 6;
  if (wg >= 512){
    __shared__ float P[8 * 256];
    for (int i = tid; i < 2048; i += 256) P[i] = fdec(pooledEnc[i]);
    __syncthreads();
    const int r = (wg - 512) * 4 + w;
    if (r >= 8385) return;
    float4 c4 = ((const float4*)(cw + (size_t)r * 256))[lane];
    float bias = cb[r];
    #pragma unroll
    for (int b = 0; b < 8; b++){
      const float* pbp = P + b * 256 + lane * 4;
      float s = c4.x * pbp[0] + c4.y * pbp[1] + c4.z * pbp[2] + c4.w * pbp[3];
      #pragma unroll
      for (int d = 1; d < 64; d <<= 1) s += __shfl_xor(s, d);
      if (lane == 0) params[b * 8385 + r] = s + bias;
    }
    return;
  }
  const int b = wg & 7, nt = wg >> 3;
  const int n0 = nt * 32;
  const int l15 = lane & 15, g = lane >> 4;
  const unsigned short* Tb = Tt + (size_t)b * 2048 * 256;

  f32x4 aqk[2][2], av[4][2];
  #pragma unroll
  for (int i = 0; i < 2; i++)
    #pragma unroll
    for (int nf = 0; nf < 2; nf++) aqk[i][nf] = (f32x4){0.f,0.f,0.f,0.f};
  #pragma unroll
  for (int j = 0; j < 4; j++)
    #pragma unroll
    for (int nf = 0; nf < 2; nf++) av[j][nf] = (f32x4){0.f,0.f,0.f,0.f};

  #pragma unroll 2
  for (int kc = 0; kc < 8; kc++){
    short8 bfr[2];
    #pragma unroll
    for (int nf = 0; nf < 2; nf++)
      bfr[nf] = *(const short8*)(Tb + (size_t)(n0 + nf * 16 + l15) * 256 + kc * 32 + g * 8);
    short8 aq[2];
    #pragma unroll
    for (int i = 0; i < 2; i++)
      aq[i] = *(const short8*)(Wbf + (size_t)((2 * w + i) * 16 + l15) * 256 + kc * 32 + g * 8);
    short8 afv[4];
    #pragma unroll
    for (int j = 0; j < 4; j++)
      afv[j] = *(const short8*)(Wbf + (size_t)(128 + (4 * w + j) * 16 + l15) * 256 + kc * 32 + g * 8);
    #pragma unroll
    for (int i = 0; i < 2; i++)
      #pragma unroll
      for (int nf = 0; nf < 2; nf++)
        aqk[i][nf] = __builtin_amdgcn_mfma_f32_16x16x32_bf16(aq[i], bfr[nf], aqk[i][nf], 0, 0, 0);
    #pragma unroll
    for (int j = 0; j < 4; j++)
      #pragma unroll
      for (int nf = 0; nf < 2; nf++)
        av[j][nf] = __builtin_amdgcn_mfma_f32_16x16x32_bf16(bfr[nf], afv[j], av[j][nf], 0, 0, 0);
  }
  unsigned short* qk = (w < 2) ? qo : ko;
  #pragma unroll
  for (int i = 0; i < 2; i++)
    #pragma unroll
    for (int nf = 0; nf < 2; nf++){
      int n = n0 + nf * 16 + l15;
      int cbase = (w & 1) * 32 + i * 16 + g * 4;
      short4v pk;
      #pragma unroll
      for (int r = 0; r < 4; r++) pk[r] = (short)f2bf(aqk[i][nf][r]);
      *(short4v*)(qk + ((size_t)b * 2048 + n) * 64 + cbase) = pk;
    }
  #pragma unroll
  for (int j = 0; j < 4; j++)
    #pragma unroll
    for (int nf = 0; nf < 2; nf++){
      int o = (4 * w + j) * 16 + l15;
      int nb2 = n0 + nf * 16 + g * 4;
      unsigned pv8 = 0;
      #pragma unroll
      for (int r = 0; r < 4; r++)
        pv8 |= (unsigned)f2e4m3(av[j][nf][r]) << (8 * r);
      *(unsigned*)(vt8 + ((size_t)b * 256 + o) * 2048 + nb2) = pv8;
    }
}

// ---------------- kA v5: swapped QK -> P fp8 row-major [q][2048] -----------------
__global__ __launch_bounds__(512, 4) void kA_scores(
    const unsigned short* __restrict__ Qg, const unsigned short* __restrict__ Kg,
    unsigned char* __restrict__ Pg, float* __restrict__ sbuf,
    int b0, int bshift){
  const int wg = blockIdx.x;
  const int bmask = (1 << bshift) - 1;
  const int b = b0 + (wg & bmask);
  const int q0 = (wg >> bshift) * 32;
  const int tid = threadIdx.x, lane = tid & 63, w = tid >> 6;
  const int l15 = lane & 15, g = lane >> 4;
  __shared__ float wsum[32][8];
  const unsigned short* Qb = Qg + (size_t)b * 2048 * 64;
  const unsigned short* Kb = Kg + (size_t)b * 2048 * 64;
  unsigned char* Pb = Pg + (size_t)(wg & bmask) * 2048 * 2048;

  short8 qf[2][2];
  #pragma unroll
  for (int qi = 0; qi < 2; qi++)
    #pragma unroll
    for (int kc = 0; kc < 2; kc++)
      qf[qi][kc] = *(const short8*)(Qb + (size_t)(q0 + qi * 16 + l15) * 64 + kc * 32 + g * 8);

  float ps[2] = {0.f, 0.f};                   // per-lane partial for q = qi*16+l15

  const int wm0 = w * 256;
  #pragma unroll
  for (int mt = 0; mt < 4; ++mt){
    const int mb = wm0 + mt * 64;
    short8 kf[4][2];
    #pragma unroll
    for (int mi = 0; mi < 4; mi++)
      #pragma unroll
      for (int kc = 0; kc < 2; kc++)
        kf[mi][kc] = *(const short8*)(Kb + (size_t)(mb + mi * 16 + l15) * 64 + kc * 32 + g * 8);
    #pragma unroll
    for (int qi = 0; qi < 2; qi++){
      f32x4 sa[4];
      #pragma unroll
      for (int mi = 0; mi < 4; mi++) sa[mi] = (f32x4){0.f,0.f,0.f,0.f};
      #pragma unroll
      for (int mi = 0; mi < 4; mi++)
        #pragma unroll
        for (int kc = 0; kc < 2; kc++)
          sa[mi] = __builtin_amdgcn_mfma_f32_16x16x32_bf16(kf[mi][kc], qf[qi][kc], sa[mi], 0, 0, 0);
      #pragma unroll
      for (int mi = 0; mi < 4; mi++){
        unsigned pk8 = 0;
        #pragma unroll
        for (int r = 0; r < 4; r++){
          float p = __expf(sa[mi][r]);        // sa[mi][r] = S[m=mb+mi*16+g*4+r][q]
          ps[qi] += p;
          pk8 |= (unsigned)f2e4m3(p) << (8 * r);
        }
        *(unsigned*)(Pb + (size_t)(q0 + qi * 16 + l15) * 2048 + mb + mi * 16 + g * 4) = pk8;
      }
    }
  }
  #pragma unroll
  for (int qi = 0; qi < 2; qi++){
    float t = ps[qi];
    t += __shfl_xor(t, 16);
    t += __shfl_xor(t, 32);                   // sum over the 4 g-groups
    if (lane < 16) wsum[qi * 16 + l15][w] = t;
  }
  __syncthreads();
  if (tid < 32){
    float t = 0.f;
    #pragma unroll
    for (int i = 0; i < 8; i++) t += wsum[tid][i];
    sbuf[(size_t)b * 2048 + q0 + tid] = t;
  }
}

// ---------------- kB v7: O = P8@V8^T via MX-scaled fp8 MFMA (K=128) --------------
__global__ __launch_bounds__(256, 3) void kB_pv(
    const unsigned char* __restrict__ Pg, const unsigned char* __restrict__ Vt,
    const float* __restrict__ sbuf, unsigned* __restrict__ tmaxe,
    int b0, int bshift){
  const int wg = blockIdx.x;
  const int bmask = (1 << bshift) - 1;
  const int b = b0 + (wg & bmask);
  const int rest = wg >> bshift;
  const int oh = rest & 1;
  const int n0 = (rest >> 1) * 64;
  const int tid = threadIdx.x, lane = tid & 63, w = tid >> 6;
  const int l15 = lane & 15, g = lane >> 4;
  __shared__ __align__(32) unsigned char smem[2][24576];  // dbuf: Pl 8KB | Vl 16KB

  const unsigned char* Pb = Pg + (size_t)(wg & bmask) * 2048 * 2048;
  const unsigned char* Vb = Vt + ((size_t)b * 256 + oh * 128) * 2048;

  f32x4 acc[4][2];
  #pragma unroll
  for (int ni = 0; ni < 4; ni++)
    #pragma unroll
    for (int oi = 0; oi < 2; oi++) acc[ni][oi] = (f32x4){0.f,0.f,0.f,0.f};

  const unsigned char* psrc[6];
  {
    #pragma unroll
    for (int k = 0; k < 6; k++){
      int d = k * 4096 + w * 1024 + lane * 16;
      if (k < 2){                                        // P: 64 rows x 128B
        int row = d >> 7;
        int colB = (d & 127) ^ ((row & 3) << 5);
        psrc[k] = Pb + (size_t)(n0 + row) * 2048 + colB;
      } else {                                           // V-half: 128 rows x 128B
        int dv = d - 8192;
        int row = dv >> 7;
        int colB = (dv & 127) ^ ((row & 3) << 5);
        psrc[k] = Vb + (size_t)row * 2048 + colB;
      }
    }
  }
  auto ISSUE = [&](int m0, int bufIdx){
    #pragma unroll
    for (int k = 0; k < 6; k++){
      unsigned char* dst = &smem[bufIdx][k * 4096 + w * 1024];  // wave-uniform
      __builtin_amdgcn_global_load_lds(
          (const __attribute__((address_space(1))) void*)(psrc[k] + m0),
          (__attribute__((address_space(3))) void*)dst, 16, 0, 0);
    }
  };

  ISSUE(0, 0);
  __syncthreads();                                     // drains vmcnt: buf0 ready

  const int SC = 0x7F7F7F7F;                           // E8M0 1.0 per block
  for (int t = 0; t < 16; ++t){
    unsigned char* cur = smem[t & 1];
    if (t < 15) ISSUE((t + 1) * 128, (t + 1) & 1);     // async into other buffer
    int8v af[4], bf[2];
    #pragma unroll
    for (int ni = 0; ni < 4; ni++){
      int row = ni * 16 + l15;
      af[ni] = *(const int8v*)(cur + row * 128 + ((g * 32) ^ ((row & 3) << 5)));
    }
    #pragma unroll
    for (int oi = 0; oi < 2; oi++){
      int row = w * 32 + oi * 16 + l15;
      bf[oi] = *(const int8v*)(cur + 8192 + row * 128 + ((g * 32) ^ ((row & 3) << 5)));
    }
    #pragma unroll
    for (int ni = 0; ni < 4; ni++)
      #pragma unroll
      for (int oi = 0; oi < 2; oi++)
        acc[ni][oi] = __builtin_amdgcn_mfma_scale_f32_16x16x128_f8f6f4(
            af[ni], bf[oi], acc[ni][oi], 0, 0, 0, SC, 0, SC);
    if (t < 15)
      __syncthreads();                                 // next buf ready; cur reads done
  }
  float inv[4][4];
  #pragma unroll
  for (int ni = 0; ni < 4; ni++)
    #pragma unroll
    for (int r = 0; r < 4; r++)
      inv[ni][r] = 1.0f / sbuf[(size_t)b * 2048 + n0 + ni * 16 + g * 4 + r];
  #pragma unroll
  for (int oi = 0; oi < 2; oi++){
    float cm = -1e30f;
    #pragma unroll
    for (int ni = 0; ni < 4; ni++)
      #pragma unroll
      for (int r = 0; r < 4; r++)
        cm = fmaxf(cm, acc[ni][oi][r] * inv[ni][r]);
    cm = fmaxf(cm, __shfl_xor(cm, 16));
    cm = fmaxf(cm, __shfl_xor(cm, 32));
    if (lane < 16)
      atomicMax(&tmaxe[b * 256 + oh * 128 + w * 32 + oi * 16 + lane], fenc(cm));
  }
}

// ---------------- K5: W_eff = P0 + P1*t + P2 (bf16); bias_eff; w0/w1 -> bf16 -----
__global__ __launch_bounds__(256) void k5_weff(const float* __restrict__ proj_w,
    const float* __restrict__ proj_b, const unsigned* __restrict__ tmaxe,
    const float* __restrict__ params, unsigned short* __restrict__ weff,
    float* __restrict__ beff, unsigned short* __restrict__ w0b,
    unsigned short* __restrict__ w1b){
  const int b = blockIdx.y, o = blockIdx.x;
  const int c = threadIdx.x;                  // 256
  float t = fdec(tmaxe[b * 256 + c]);
  float p0 = proj_w[o * 768 + c];
  float p1 = proj_w[o * 768 + 256 + c];
  float p2 = proj_w[o * 768 + 512 + c];
  weff[((size_t)b * 64 + o) * 256 + c] = f2bf(p0 + p1 * t + p2);
  float s = p0 * t;
  #pragma unroll
  for (int d = 1; d < 64; d <<= 1) s += __shfl_xor(s, d);
  __shared__ float sm[4];
  if ((c & 63) == 0) sm[c >> 6] = s;
  __syncthreads();
  if (c == 0) beff[b * 64 + o] = proj_b[o] - (sm[0] + sm[1] + sm[2] + sm[3]);
  if (c < 64)        w0b[((size_t)b * 64 + o) * 64 + c] = f2bf(params[b * 8385 + o * 64 + c]);
  else if (c < 128)  w1b[((size_t)b * 64 + o) * 64 + (c - 64)] = f2bf(params[b * 8385 + 4096 + o * 64 + (c - 64)]);
}

// ---------------- K6 (R15 form, n-tile 128): fused scene MLP ---------------------
// grid (128, 8) x 256 thr; 32KB LDS -> 5 WG/CU (was 2). Two-barrier k-loop,
// register prefetch, global weff A-frags — numerics identical to R15.
__global__ __launch_bounds__(256) void k6_main(const float* __restrict__ Sg,
    const unsigned short* __restrict__ weff, const float* __restrict__ beff,
    const unsigned short* __restrict__ w0b, const unsigned short* __restrict__ w1b,
    const float* __restrict__ params, float* __restrict__ out){
  const int b = blockIdx.y, nt = blockIdx.x;
  const int n0 = nt * 128;
  const int tid = threadIdx.x, lane = tid & 63, w = tid >> 6;
  const int l15 = lane & 15, g = lane >> 4;
  __shared__ __align__(16) unsigned char smem[32768];
  unsigned short* H0 = (unsigned short*)smem;            // [128 n][64 o] bf16, 16 KB
  unsigned char*  Ub = smem + 16384;                     // Bs (8 KB) then H1 (16 KB)
  unsigned short* H1 = (unsigned short*)Ub;

  const float* Sb = Sg + (size_t)b * 256 * 16384;
  const unsigned short* We = weff + (size_t)b * 64 * 256;
  f32x4 a0[4][2];
  #pragma unroll
  for (int mi = 0; mi < 4; mi++)
    #pragma unroll
    for (int ni = 0; ni < 2; ni++) a0[mi][ni] = (f32x4){0.f,0.f,0.f,0.f};

  const int scc = tid & 31;                   // c row within k-tile
  const int snb = (tid >> 5) * 16;            // 8 groups x 16 n = 128 n
  const float* src0 = Sb + (size_t)scc * 16384 + n0 + snb;
  float4 v0 = ((const float4*)src0)[0];
  float4 v1 = ((const float4*)src0)[1];
  float4 v2 = ((const float4*)src0)[2];
  float4 v3 = ((const float4*)src0)[3];
  for (int k0 = 0; k0 < 256; k0 += 32){
    float vals[16] = {v0.x,v0.y,v0.z,v0.w, v1.x,v1.y,v1.z,v1.w,
                      v2.x,v2.y,v2.z,v2.w, v3.x,v3.y,v3.z,v3.w};
    #pragma unroll
    for (int j = 0; j < 16; j++){
      int n = snb + j;
      unsigned byteo = ((unsigned)(n * 64 + scc * 2)) ^ ((unsigned)((n >> 1) & 3) << 4);
      *(unsigned short*)(Ub + byteo) = f2bf(vals[j]);
    }
    if (k0 < 224){                            // prefetch next k-tile into regs
      const float* nsrc = Sb + (size_t)(k0 + 32 + scc) * 16384 + n0 + snb;
      v0 = ((const float4*)nsrc)[0];
      v1 = ((const float4*)nsrc)[1];
      v2 = ((const float4*)nsrc)[2];
      v3 = ((const float4*)nsrc)[3];
    }
    __syncthreads();
    short8 bf0[2];
    #pragma unroll
    for (int ni = 0; ni < 2; ni++){
      int n = w * 32 + ni * 16 + l15;
      bf0[ni] = *(const short8*)(Ub + (((unsigned)(n * 64 + g * 16)) ^ ((unsigned)((n >> 1) & 3) << 4)));
    }
    #pragma unroll
    for (int mi = 0; mi < 4; mi++){
      short8 af = *(const short8*)(We + (size_t)(mi * 16 + l15) * 256 + k0 + g * 8);
      #pragma unroll
      for (int ni = 0; ni < 2; ni++)
        a0[mi][ni] = __builtin_amdgcn_mfma_f32_16x16x32_bf16(af, bf0[ni], a0[mi][ni], 0, 0, 0);
    }
    __syncthreads();
  }
  const float* be = beff + b * 64;
  #pragma unroll
  for (int mi = 0; mi < 4; mi++)
    #pragma unroll
    for (int ni = 0; ni < 2; ni++){
      int n = w * 32 + ni * 16 + l15;
      unsigned base = ((unsigned)(n * 128 + mi * 32 + g * 8)) ^ ((unsigned)((n & 7) << 4));
      unsigned short hh[4];
      #pragma unroll
      for (int r = 0; r < 4; r++){
        int o = mi * 16 + g * 4 + r;
        hh[r] = f2bf(fmaxf(a0[mi][ni][r] + be[o], 0.f));
      }
      *(unsigned*)((unsigned char*)H0 + base)     = (unsigned)hh[0] | ((unsigned)hh[1] << 16);
      *(unsigned*)((unsigned char*)H0 + base + 4) = (unsigned)hh[2] | ((unsigned)hh[3] << 16);
    }
  __syncthreads();
  f32x4 a1[4][2];
  #pragma unroll
  for (int mi = 0; mi < 4; mi++)
    #pragma unroll
    for (int ni = 0; ni < 2; ni++) a1[mi][ni] = (f32x4){0.f,0.f,0.f,0.f};
  const unsigned short* W0 = w0b + (size_t)b * 4096;
  #pragma unroll
  for (int ks = 0; ks < 2; ks++){
    short8 bfh[2];
    #pragma unroll
    for (int ni = 0; ni < 2; ni++){
      int n = w * 32 + ni * 16 + l15;
      unsigned off = ((unsigned)(n * 128 + ks * 64 + g * 16)) ^ ((unsigned)((n & 7) << 4));
      bfh[ni] = *(const short8*)((unsigned char*)H0 + off);
    }
    #pragma unroll
    for (int mi = 0; mi < 4; mi++){
      short8 af = *(const short8*)(W0 + (mi * 16 + l15) * 64 + ks * 32 + g * 8);
      #pragma unroll
      for (int ni = 0; ni < 2; ni++)
        a1[mi][ni] = __builtin_amdgcn_mfma_f32_16x16x32_bf16(af, bfh[ni], a1[mi][ni], 0, 0, 0);
    }
  }
  const float* pp = params + (size_t)b * 8385;
  const float* b0p = pp + 8256;
  #pragma unroll
  for (int mi = 0; mi < 4; mi++)
    #pragma unroll
    for (int ni = 0; ni < 2; ni++){
      int n = w * 32 + ni * 16 + l15;
      unsigned base = ((unsigned)(n * 128 + mi * 32 + g * 8)) ^ ((unsigned)((n & 7) << 4));
      unsigned short hh[4];
      #pragma unroll
      for (int r = 0; r < 4; r++){
        int o = mi * 16 + g * 4 + r;
        hh[r] = f2bf(fmaxf(a1[mi][ni][r] + b0p[o], 0.f));
      }
      *(unsigned*)((unsigned char*)H1 + base)     = (unsigned)hh[0] | ((unsigned)hh[1] << 16);
      *(unsigned*)((unsigned char*)H1 + base + 4) = (unsigned)hh[2] | ((unsigned)hh[3] << 16);
    }
  __syncthreads();
  f32x4 a2[4][2];
  #pragma unroll
  for (int mi = 0; mi < 4; mi++)
    #pragma unroll
    for (int ni = 0; ni < 2; ni++) a2[mi][ni] = (f32x4){0.f,0.f,0.f,0.f};
  const unsigned short* W1 = w1b + (size_t)b * 4096;
  #pragma unroll
  for (int ks = 0; ks < 2; ks++){
    short8 bfh[2];
    #pragma unroll
    for (int ni = 0; ni < 2; ni++){
      int n = w * 32 + ni * 16 + l15;
      unsigned off = ((unsigned)(n * 128 + ks * 64 + g * 16)) ^ ((unsigned)((n & 7) << 4));
      bfh[ni] = *(const short8*)((unsigned char*)H1 + off);
    }
    #pragma unroll
    for (int mi = 0; mi < 4; mi++){
      short8 af = *(const short8*)(W1 + (mi * 16 + l15) * 64 + ks * 32 + g * 8);
      #pragma unroll
      for (int ni = 0; ni < 2; ni++)
        a2[mi][ni] = __builtin_amdgcn_mfma_f32_16x16x32_bf16(af, bfh[ni], a2[mi][ni], 0, 0, 0);
    }
  }
  const float* b1p = pp + 8320;
  const float* w2p = pp + 8192;
  float b2v = pp[8384];
  #pragma unroll
  for (int ni = 0; ni < 2; ni++){
    float t = 0.f;
    #pragma unroll
    for (int mi = 0; mi < 4; mi++)
      #pragma unroll
      for (int r = 0; r < 4; r++){
        int o = mi * 16 + g * 4 + r;
        t += w2p[o] * fmaxf(a2[mi][ni][r] + b1p[o], 0.f);
      }
    t += __shfl_xor(t, 16);
    t += __shfl_xor(t, 32);
    if (lane < 16)
      out[(size_t)b * 16384 + n0 + w * 32 + ni * 16 + l15] = t + b2v;
  }
}

extern "C" void kernel_launch(void* const* d_in, const int* in_sizes, int n_in,
                              void* d_out, int out_size, void* d_ws, size_t ws_size,
                              hipStream_t stream){
  const float* scene = (const float*)d_in[0];
  const float* tmpl  = (const float*)d_in[1];
  const float* qw    = (const float*)d_in[2];
  const float* kw    = (const float*)d_in[3];
  const float* vw    = (const float*)d_in[4];
  const float* pw    = (const float*)d_in[5];
  const float* pb    = (const float*)d_in[6];
  const float* cw    = (const float*)d_in[7];
  const float* cb    = (const float*)d_in[8];
  float* out = (float*)d_out;
  char* ws = (char*)d_ws;

  unsigned short* Q      = (unsigned short*)(ws + 0);                    // 2 MB
  unsigned short* K      = (unsigned short*)(ws + (2u << 20));           // 2 MB
  unsigned char*  V8     = (unsigned char*)(ws + (4u << 20));            // 4 MB
  unsigned*       pooledEnc = (unsigned*)(ws + (12u << 20));             // 8 KB
  unsigned*       tmaxe  = (unsigned*)(ws + (12u << 20) + 8192);         // 8 KB
  float*          params = (float*)(ws + (12u << 20) + 16384);           // 268 KB
  unsigned short* w0b    = (unsigned short*)(ws + (13u << 20));          // 64 KB
  unsigned short* w1b    = (unsigned short*)(ws + (13u << 20) + 65536);  // 64 KB
  unsigned short* weff   = (unsigned short*)(ws + (13u << 20) + 131072); // 256 KB
  float*          beff   = (float*)(ws + (13u << 20) + 131072 + 262144); // 2 KB
  float*          sbuf   = (float*)(ws + (14u << 20));                   // 64 KB
  unsigned short* Wbf    = (unsigned short*)(ws + (14u << 20) + 131072); // 192 KB
  unsigned char*  P8buf  = (unsigned char*)(ws + (16u << 20));           // up to 33.5 MB
  unsigned short* Tt     = (unsigned short*)P8buf;  // 8 MB; dead before kA writes

  const size_t pPerBatch = (size_t)2048 * 2048;     // 4 MB fp8 per batch
  size_t avail = ws_size > (16u << 20) ? ws_size - (16u << 20) : 0;
  int nb = 8, bshift = 3;
  while (nb > 1 && (size_t)nb * pPerBatch > avail){ nb >>= 1; bshift--; }

  hipMemsetAsync(ws + (12u << 20), 0, 16384, stream);   // pooledEnc + tmaxe floors
  k0_tt<<<dim3(1120), dim3(256), 0, stream>>>(tmpl, Tt, pooledEnc, qw, kw, vw, Wbf);
  k23_qkv_params<<<dim3(512 + 2097), dim3(256), 0, stream>>>(Wbf, Tt, Q, K, V8,
                                                             pooledEnc, cw, cb, params);
  for (int b0 = 0; b0 < 8; b0 += nb){
    kA_scores<<<dim3(64 * nb), dim3(512), 0, stream>>>(Q, K, P8buf, sbuf, b0, bshift);
    kB_pv<<<dim3(64 * nb), dim3(256), 0, stream>>>(P8buf, V8, sbuf, tmaxe, b0, bshift);
  }
  k5_weff<<<dim3(64, 8), dim3(256), 0, stream>>>(pw, pb, tmaxe, params, weff, beff, w0b, w1b);
  k6_main<<<dim3(128, 8), dim3(256), 0, stream>>>(scene, weff, beff, w0b, w1b, params, out);
}

// Round 22
// 123.739 us; speedup vs baseline: 1.3546x; 1.0569x over previous
//
#include <hip/hip_runtime.h>
#include <hip/hip_fp8.h>

// DynamicConvolution fused pipeline for MI355X (gfx950).
// R22 (base = R21, 130.8): k6's k-loop rebuilt in kB's proven skeleton:
// scene staged f32 UNTRANSPOSED into 2x16KB LDS dbuf via global_load_lds
// (pure async DMA, no register/VALU coupling), ISSUE(t+1) before compute(t),
// ONE barrier per tile. Transpose+bf16 conversion moved to the read side
// (8 scalar ds_read_b32 + f2bf per frag; ~4-way banks = 1.58x, VALU has 87%
// headroom). H0/H1 epilogue overlays the dbuf after the loop (32KB LDS).
// All other kernels byte-identical to R21.
// Stages: memset -> k0_tt(+weights) -> k23 qkv+params -> kA exp(QK^T) ->
//         kB PV+tmax (MX fp8) -> k5 W_eff -> k6 fused scene MLP.

typedef __attribute__((ext_vector_type(8))) short short8;
typedef __attribute__((ext_vector_type(4))) short short4v;
typedef __attribute__((ext_vector_type(4))) float f32x4;
typedef __attribute__((ext_vector_type(8))) int int8v;

__device__ __forceinline__ unsigned short f2bf(float f){
  unsigned u = __float_as_uint(f);
  u += 0x7FFFu + ((u >> 16) & 1u);           // round-to-nearest-even
  return (unsigned short)(u >> 16);
}
__device__ __forceinline__ unsigned char f2e4m3(float f){
  return __hip_fp8_e4m3(f).__x;              // OCP e4m3 (gfx950 HW format)
}
// monotone float<->uint for atomicMax on floats (incl. negatives)
__device__ __forceinline__ unsigned fenc(float f){
  unsigned u = __float_as_uint(f);
  return (u & 0x80000000u) ? ~u : (u | 0x80000000u);
}
__device__ __forceinline__ float fdec(unsigned k){
  unsigned u = (k & 0x80000000u) ? (k & 0x7FFFFFFFu) : ~k;
  return __uint_as_float(u);
}

// ---------------- k0_tt: Tt[b][n][c] = bf16(T[b][c][n]) + pooled max;
//                  wg>=1024: Wbf[384][256] bf16 (q*0.125 folded) ----------------
__global__ __launch_bounds__(256) void k0_tt(const float* __restrict__ T,
    unsigned short* __restrict__ Tt, unsigned* __restrict__ pooledEnc,
    const float* __restrict__ qw, const float* __restrict__ kw,
    const float* __restrict__ vw, unsigned short* __restrict__ Wbf){
  const int wg = blockIdx.x;
  const int tid = threadIdx.x;
  if (wg >= 1024){                            // weight conversion (96 WGs)
    const int e = ((wg - 1024) * 256 + tid) * 4;
    const int row = e >> 8, c = e & 255;
    const float* src;
    float scl = 1.0f;
    if (row < 64){ src = qw + row * 256 + c; scl = 0.125f; }
    else if (row < 128){ src = kw + (row - 64) * 256 + c; }
    else { src = vw + (row - 128) * 256 + c; }
    float4 v = *(const float4*)src;
    short4v o;
    o[0] = (short)f2bf(v.x * scl); o[1] = (short)f2bf(v.y * scl);
    o[2] = (short)f2bf(v.z * scl); o[3] = (short)f2bf(v.w * scl);
    *(short4v*)(Wbf + e) = o;
    return;
  }
  const int b = wg & 7, nt = (wg >> 3) & 15, ct = wg >> 7;
  const int n0 = nt * 128, c0 = ct * 32;
  __shared__ float Ls[32][129];
  const int cr = tid >> 3, nq = tid & 7;      // 32 c-rows x 8 n-chunks(16 f32)
  const float* src = T + ((size_t)b * 256 + c0 + cr) * 2048 + n0 + nq * 16;
  float4 v0 = ((const float4*)src)[0];
  float4 v1 = ((const float4*)src)[1];
  float4 v2 = ((const float4*)src)[2];
  float4 v3 = ((const float4*)src)[3];
  float mx = fmaxf(fmaxf(fmaxf(v0.x, v0.y), fmaxf(v0.z, v0.w)),
                   fmaxf(fmaxf(v1.x, v1.y), fmaxf(v1.z, v1.w)));
  mx = fmaxf(mx, fmaxf(fmaxf(fmaxf(v2.x, v2.y), fmaxf(v2.z, v2.w)),
                       fmaxf(fmaxf(v3.x, v3.y), fmaxf(v3.z, v3.w))));
  mx = fmaxf(mx, __shfl_xor(mx, 1));
  mx = fmaxf(mx, __shfl_xor(mx, 2));
  mx = fmaxf(mx, __shfl_xor(mx, 4));
  if (nq == 0) atomicMax(&pooledEnc[b * 256 + c0 + cr], fenc(mx));
  float* lr = &Ls[cr][nq * 16];
  *(float4*)lr = v0; *(float4*)(lr + 4) = v1;
  *(float4*)(lr + 8) = v2; *(float4*)(lr + 12) = v3;
  __syncthreads();
  const int nr = tid >> 1, ch = tid & 1;      // 128 n-rows x 2 c-halves(16)
  unsigned short ob[16];
  #pragma unroll
  for (int j = 0; j < 16; j++) ob[j] = f2bf(Ls[ch * 16 + j][nr]);
  unsigned short* dst = Tt + ((size_t)b * 2048 + n0 + nr) * 256 + c0 + ch * 16;
  *(short8*)dst = *(short8*)&ob[0];
  *(short8*)(dst + 8) = *(short8*)&ob[8];
}

// ---------------- k23: fused k2 (QKV gemm, wg<512) + k3 (params gemv) ------------
__global__ __launch_bounds__(256) void k23_qkv_params(
    const unsigned short* __restrict__ Wbf, const unsigned short* __restrict__ Tt,
    unsigned short* __restrict__ qo, unsigned short* __restrict__ ko,
    unsigned char* __restrict__ vt8,
    const unsigned* __restrict__ pooledEnc, const float* __restrict__ cw,
    const float* __restrict__ cb, float* __restrict__ params){
  const int wg = blockIdx.x;
  const int tid = threadIdx.x, lane = tid & 63, w = tid >> 6;
  if (wg >= 512){
    __shared__ float P[8 * 256];
    for (int i = tid; i < 2048; i += 256) P[i] = fdec(pooledEnc[i]);
    __syncthreads();
    const int r = (wg - 512) * 4 + w;
    if (r >= 8385) return;
    float4 c4 = ((const float4*)(cw + (size_t)r * 256))[lane];
    float bias = cb[r];
    #pragma unroll
    for (int b = 0; b < 8; b++){
      const float* pbp = P + b * 256 + lane * 4;
      float s = c4.x * pbp[0] + c4.y * pbp[1] + c4.z * pbp[2] + c4.w * pbp[3];
      #pragma unroll
      for (int d = 1; d < 64; d <<= 1) s += __shfl_xor(s, d);
      if (lane == 0) params[b * 8385 + r] = s + bias;
    }
    return;
  }
  const int b = wg & 7, nt = wg >> 3;
  const int n0 = nt * 32;
  const int l15 = lane & 15, g = lane >> 4;
  const unsigned short* Tb = Tt + (size_t)b * 2048 * 256;

  f32x4 aqk[2][2], av[4][2];
  #pragma unroll
  for (int i = 0; i < 2; i++)
    #pragma unroll
    for (int nf = 0; nf < 2; nf++) aqk[i][nf] = (f32x4){0.f,0.f,0.f,0.f};
  #pragma unroll
  for (int j = 0; j < 4; j++)
    #pragma unroll
    for (int nf = 0; nf < 2; nf++) av[j][nf] = (f32x4){0.f,0.f,0.f,0.f};

  #pragma unroll 2
  for (int kc = 0; kc < 8; kc++){
    short8 bfr[2];
    #pragma unroll
    for (int nf = 0; nf < 2; nf++)
      bfr[nf] = *(const short8*)(Tb + (size_t)(n0 + nf * 16 + l15) * 256 + kc * 32 + g * 8);
    short8 aq[2];
    #pragma unroll
    for (int i = 0; i < 2; i++)
      aq[i] = *(const short8*)(Wbf + (size_t)((2 * w + i) * 16 + l15) * 256 + kc * 32 + g * 8);
    short8 afv[4];
    #pragma unroll
    for (int j = 0; j < 4; j++)
      afv[j] = *(const short8*)(Wbf + (size_t)(128 + (4 * w + j) * 16 + l15) * 256 + kc * 32 + g * 8);
    #pragma unroll
    for (int i = 0; i < 2; i++)
      #pragma unroll
      for (int nf = 0; nf < 2; nf++)
        aqk[i][nf] = __builtin_amdgcn_mfma_f32_16x16x32_bf16(aq[i], bfr[nf], aqk[i][nf], 0, 0, 0);
    #pragma unroll
    for (int j = 0; j < 4; j++)
      #pragma unroll
      for (int nf = 0; nf < 2; nf++)
        av[j][nf] = __builtin_amdgcn_mfma_f32_16x16x32_bf16(bfr[nf], afv[j], av[j][nf], 0, 0, 0);
  }
  unsigned short* qk = (w < 2) ? qo : ko;
  #pragma unroll
  for (int i = 0; i < 2; i++)
    #pragma unroll
    for (int nf = 0; nf < 2; nf++){
      int n = n0 + nf * 16 + l15;
      int cbase = (w & 1) * 32 + i * 16 + g * 4;
      short4v pk;
      #pragma unroll
      for (int r = 0; r < 4; r++) pk[r] = (short)f2bf(aqk[i][nf][r]);
      *(short4v*)(qk + ((size_t)b * 2048 + n) * 64 + cbase) = pk;
    }
  #pragma unroll
  for (int j = 0; j < 4; j++)
    #pragma unroll
    for (int nf = 0; nf < 2; nf++){
      int o = (4 * w + j) * 16 + l15;
      int nb2 = n0 + nf * 16 + g * 4;
      unsigned pv8 = 0;
      #pragma unroll
      for (int r = 0; r < 4; r++)
        pv8 |= (unsigned)f2e4m3(av[j][nf][r]) << (8 * r);
      *(unsigned*)(vt8 + ((size_t)b * 256 + o) * 2048 + nb2) = pv8;
    }
}

// ---------------- kA v5: swapped QK -> P fp8 row-major [q][2048] -----------------
__global__ __launch_bounds__(512, 4) void kA_scores(
    const unsigned short* __restrict__ Qg, const unsigned short* __restrict__ Kg,
    unsigned char* __restrict__ Pg, float* __restrict__ sbuf,
    int b0, int bshift){
  const int wg = blockIdx.x;
  const int bmask = (1 << bshift) - 1;
  const int b = b0 + (wg & bmask);
  const int q0 = (wg >> bshift) * 32;
  const int tid = threadIdx.x, lane = tid & 63, w = tid >> 6;
  const int l15 = lane & 15, g = lane >> 4;
  __shared__ float wsum[32][8];
  const unsigned short* Qb = Qg + (size_t)b * 2048 * 64;
  const unsigned short* Kb = Kg + (size_t)b * 2048 * 64;
  unsigned char* Pb = Pg + (size_t)(wg & bmask) * 2048 * 2048;

  short8 qf[2][2];
  #pragma unroll
  for (int qi = 0; qi < 2; qi++)
    #pragma unroll
    for (int kc = 0; kc < 2; kc++)
      qf[qi][kc] = *(const short8*)(Qb + (size_t)(q0 + qi * 16 + l15) * 64 + kc * 32 + g * 8);

  float ps[2] = {0.f, 0.f};                   // per-lane partial for q = qi*16+l15

  const int wm0 = w * 256;
  #pragma unroll
  for (int mt = 0; mt < 4; ++mt){
    const int mb = wm0 + mt * 64;
    short8 kf[4][2];
    #pragma unroll
    for (int mi = 0; mi < 4; mi++)
      #pragma unroll
      for (int kc = 0; kc < 2; kc++)
        kf[mi][kc] = *(const short8*)(Kb + (size_t)(mb + mi * 16 + l15) * 64 + kc * 32 + g * 8);
    #pragma unroll
    for (int qi = 0; qi < 2; qi++){
      f32x4 sa[4];
      #pragma unroll
      for (int mi = 0; mi < 4; mi++) sa[mi] = (f32x4){0.f,0.f,0.f,0.f};
      #pragma unroll
      for (int mi = 0; mi < 4; mi++)
        #pragma unroll
        for (int kc = 0; kc < 2; kc++)
          sa[mi] = __builtin_amdgcn_mfma_f32_16x16x32_bf16(kf[mi][kc], qf[qi][kc], sa[mi], 0, 0, 0);
      #pragma unroll
      for (int mi = 0; mi < 4; mi++){
        unsigned pk8 = 0;
        #pragma unroll
        for (int r = 0; r < 4; r++){
          float p = __expf(sa[mi][r]);        // sa[mi][r] = S[m=mb+mi*16+g*4+r][q]
          ps[qi] += p;
          pk8 |= (unsigned)f2e4m3(p) << (8 * r);
        }
        *(unsigned*)(Pb + (size_t)(q0 + qi * 16 + l15) * 2048 + mb + mi * 16 + g * 4) = pk8;
      }
    }
  }
  #pragma unroll
  for (int qi = 0; qi < 2; qi++){
    float t = ps[qi];
    t += __shfl_xor(t, 16);
    t += __shfl_xor(t, 32);                   // sum over the 4 g-groups
    if (lane < 16) wsum[qi * 16 + l15][w] = t;
  }
  __syncthreads();
  if (tid < 32){
    float t = 0.f;
    #pragma unroll
    for (int i = 0; i < 8; i++) t += wsum[tid][i];
    sbuf[(size_t)b * 2048 + q0 + tid] = t;
  }
}

// ---------------- kB v7: O = P8@V8^T via MX-scaled fp8 MFMA (K=128) --------------
__global__ __launch_bounds__(256, 3) void kB_pv(
    const unsigned char* __restrict__ Pg, const unsigned char* __restrict__ Vt,
    const float* __restrict__ sbuf, unsigned* __restrict__ tmaxe,
    int b0, int bshift){
  const int wg = blockIdx.x;
  const int bmask = (1 << bshift) - 1;
  const int b = b0 + (wg & bmask);
  const int rest = wg >> bshift;
  const int oh = rest & 1;
  const int n0 = (rest >> 1) * 64;
  const int tid = threadIdx.x, lane = tid & 63, w = tid >> 6;
  const int l15 = lane & 15, g = lane >> 4;
  __shared__ __align__(32) unsigned char smem[2][24576];  // dbuf: Pl 8KB | Vl 16KB

  const unsigned char* Pb = Pg + (size_t)(wg & bmask) * 2048 * 2048;
  const unsigned char* Vb = Vt + ((size_t)b * 256 + oh * 128) * 2048;

  f32x4 acc[4][2];
  #pragma unroll
  for (int ni = 0; ni < 4; ni++)
    #pragma unroll
    for (int oi = 0; oi < 2; oi++) acc[ni][oi] = (f32x4){0.f,0.f,0.f,0.f};

  const unsigned char* psrc[6];
  {
    #pragma unroll
    for (int k = 0; k < 6; k++){
      int d = k * 4096 + w * 1024 + lane * 16;
      if (k < 2){                                        // P: 64 rows x 128B
        int row = d >> 7;
        int colB = (d & 127) ^ ((row & 3) << 5);
        psrc[k] = Pb + (size_t)(n0 + row) * 2048 + colB;
      } else {                                           // V-half: 128 rows x 128B
        int dv = d - 8192;
        int row = dv >> 7;
        int colB = (dv & 127) ^ ((row & 3) << 5);
        psrc[k] = Vb + (size_t)row * 2048 + colB;
      }
    }
  }
  auto ISSUE = [&](int m0, int bufIdx){
    #pragma unroll
    for (int k = 0; k < 6; k++){
      unsigned char* dst = &smem[bufIdx][k * 4096 + w * 1024];  // wave-uniform
      __builtin_amdgcn_global_load_lds(
          (const __attribute__((address_space(1))) void*)(psrc[k] + m0),
          (__attribute__((address_space(3))) void*)dst, 16, 0, 0);
    }
  };

  ISSUE(0, 0);
  __syncthreads();                                     // drains vmcnt: buf0 ready

  const int SC = 0x7F7F7F7F;                           // E8M0 1.0 per block
  for (int t = 0; t < 16; ++t){
    unsigned char* cur = smem[t & 1];
    if (t < 15) ISSUE((t + 1) * 128, (t + 1) & 1);     // async into other buffer
    int8v af[4], bf[2];
    #pragma unroll
    for (int ni = 0; ni < 4; ni++){
      int row = ni * 16 + l15;
      af[ni] = *(const int8v*)(cur + row * 128 + ((g * 32) ^ ((row & 3) << 5)));
    }
    #pragma unroll
    for (int oi = 0; oi < 2; oi++){
      int row = w * 32 + oi * 16 + l15;
      bf[oi] = *(const int8v*)(cur + 8192 + row * 128 + ((g * 32) ^ ((row & 3) << 5)));
    }
    #pragma unroll
    for (int ni = 0; ni < 4; ni++)
      #pragma unroll
      for (int oi = 0; oi < 2; oi++)
        acc[ni][oi] = __builtin_amdgcn_mfma_scale_f32_16x16x128_f8f6f4(
            af[ni], bf[oi], acc[ni][oi], 0, 0, 0, SC, 0, SC);
    if (t < 15)
      __syncthreads();                                 // next buf ready; cur reads done
  }
  float inv[4][4];
  #pragma unroll
  for (int ni = 0; ni < 4; ni++)
    #pragma unroll
    for (int r = 0; r < 4; r++)
      inv[ni][r] = 1.0f / sbuf[(size_t)b * 2048 + n0 + ni * 16 + g * 4 + r];
  #pragma unroll
  for (int oi = 0; oi < 2; oi++){
    float cm = -1e30f;
    #pragma unroll
    for (int ni = 0; ni < 4; ni++)
      #pragma unroll
      for (int r = 0; r < 4; r++)
        cm = fmaxf(cm, acc[ni][oi][r] * inv[ni][r]);
    cm = fmaxf(cm, __shfl_xor(cm, 16));
    cm = fmaxf(cm, __shfl_xor(cm, 32));
    if (lane < 16)
      atomicMax(&tmaxe[b * 256 + oh * 128 + w * 32 + oi * 16 + lane], fenc(cm));
  }
}

// ---------------- K5: W_eff = P0 + P1*t + P2 (bf16); bias_eff; w0/w1 -> bf16 -----
__global__ __launch_bounds__(256) void k5_weff(const float* __restrict__ proj_w,
    const float* __restrict__ proj_b, const unsigned* __restrict__ tmaxe,
    const float* __restrict__ params, unsigned short* __restrict__ weff,
    float* __restrict__ beff, unsigned short* __restrict__ w0b,
    unsigned short* __restrict__ w1b){
  const int b = blockIdx.y, o = blockIdx.x;
  const int c = threadIdx.x;                  // 256
  float t = fdec(tmaxe[b * 256 + c]);
  float p0 = proj_w[o * 768 + c];
  float p1 = proj_w[o * 768 + 256 + c];
  float p2 = proj_w[o * 768 + 512 + c];
  weff[((size_t)b * 64 + o) * 256 + c] = f2bf(p0 + p1 * t + p2);
  float s = p0 * t;
  #pragma unroll
  for (int d = 1; d < 64; d <<= 1) s += __shfl_xor(s, d);
  __shared__ float sm[4];
  if ((c & 63) == 0) sm[c >> 6] = s;
  __syncthreads();
  if (c == 0) beff[b * 64 + o] = proj_b[o] - (sm[0] + sm[1] + sm[2] + sm[3]);
  if (c < 64)        w0b[((size_t)b * 64 + o) * 64 + c] = f2bf(params[b * 8385 + o * 64 + c]);
  else if (c < 128)  w1b[((size_t)b * 64 + o) * 64 + (c - 64)] = f2bf(params[b * 8385 + 4096 + o * 64 + (c - 64)]);
}

// ---------------- K6 v7: kB-skeleton — async f32 staging, cvt-on-read ------------
// grid (128, 8) x 256 thr. LDS 32KB: dbuf 2x16KB [32 c][128 f32] linear;
// H0 overlays smem+0, H1 smem+16K after the loop. ISSUE: 4 global_load_lds
// (16B)/wave, wave-uniform dest + lane*16; per-lane src = 512B-contiguous
// per 32-lane half. B-frag: 8 x ds_read_b32 (+f2bf, pack). One barrier/tile.
__global__ __launch_bounds__(256) void k6_main(const float* __restrict__ Sg,
    const unsigned short* __restrict__ weff, const float* __restrict__ beff,
    const unsigned short* __restrict__ w0b, const unsigned short* __restrict__ w1b,
    const float* __restrict__ params, float* __restrict__ out){
  const int b = blockIdx.y, nt = blockIdx.x;
  const int n0 = nt * 128;
  const int tid = threadIdx.x, lane = tid & 63, w = tid >> 6;
  const int l15 = lane & 15, g = lane >> 4;
  __shared__ __align__(16) unsigned char smem[32768];   // dbuf 2x16KB; H0/H1 after
  unsigned short* H0 = (unsigned short*)smem;           // [128 n][64 o], after loop
  unsigned short* H1 = (unsigned short*)(smem + 16384);

  const float* Sb = Sg + (size_t)b * 256 * 16384;
  // per-lane sources: wave w stages rows w*8..w*8+7 (issue j -> rows w*8+j*2 +{0,1})
  const float* psrc[4];
  #pragma unroll
  for (int j = 0; j < 4; j++)
    psrc[j] = Sb + (size_t)(w * 8 + j * 2 + (lane >> 5)) * 16384 + n0 + (lane & 31) * 4;

  auto ISSUE = [&](int t, int bufIdx){
    #pragma unroll
    for (int j = 0; j < 4; j++){
      unsigned char* dst = smem + bufIdx * 16384 + w * 4096 + j * 1024;  // uniform
      __builtin_amdgcn_global_load_lds(
          (const __attribute__((address_space(1))) void*)(psrc[j] + (size_t)t * 32 * 16384),
          (__attribute__((address_space(3))) void*)dst, 16, 0, 0);
    }
  };

  const unsigned short* We = weff + (size_t)b * 64 * 256;
  f32x4 a0[4][2];
  #pragma unroll
  for (int mi = 0; mi < 4; mi++)
    #pragma unroll
    for (int ni = 0; ni < 2; ni++) a0[mi][ni] = (f32x4){0.f,0.f,0.f,0.f};

  ISSUE(0, 0);
  __syncthreads();                            // drains vmcnt: buf0 ready
  for (int t = 0; t < 8; ++t){
    const float* cur = (const float*)(smem + (t & 1) * 16384);  // [32 c][128 n] f32
    if (t < 7) ISSUE(t + 1, (t + 1) & 1);     // async into other buffer
    short8 bf0[2];
    #pragma unroll
    for (int ni = 0; ni < 2; ni++){
      int n = w * 32 + ni * 16 + l15;
      #pragma unroll
      for (int j = 0; j < 8; j++)
        bf0[ni][j] = (short)f2bf(cur[(g * 8 + j) * 128 + n]);
    }
    #pragma unroll
    for (int mi = 0; mi < 4; mi++){
      short8 af = *(const short8*)(We + (size_t)(mi * 16 + l15) * 256 + t * 32 + g * 8);
      #pragma unroll
      for (int ni = 0; ni < 2; ni++)
        a0[mi][ni] = __builtin_amdgcn_mfma_f32_16x16x32_bf16(af, bf0[ni], a0[mi][ni], 0, 0, 0);
    }
    if (t < 7)
      __syncthreads();                        // next buf ready; cur reads done
  }
  __syncthreads();                            // all dbuf reads done before H0 write
  // layer0 epilogue: relu(+beff) -> H0
  const float* be = beff + b * 64;
  #pragma unroll
  for (int mi = 0; mi < 4; mi++)
    #pragma unroll
    for (int ni = 0; ni < 2; ni++){
      int n = w * 32 + ni * 16 + l15;
      unsigned base = ((unsigned)(n * 128 + mi * 32 + g * 8)) ^ ((unsigned)((n & 7) << 4));
      unsigned short hh[4];
      #pragma unroll
      for (int r = 0; r < 4; r++){
        int o = mi * 16 + g * 4 + r;
        hh[r] = f2bf(fmaxf(a0[mi][ni][r] + be[o], 0.f));
      }
      *(unsigned*)((unsigned char*)H0 + base)     = (unsigned)hh[0] | ((unsigned)hh[1] << 16);
      *(unsigned*)((unsigned char*)H0 + base + 4) = (unsigned)hh[2] | ((unsigned)hh[3] << 16);
    }
  __syncthreads();
  f32x4 a1[4][2];
  #pragma unroll
  for (int mi = 0; mi < 4; mi++)
    #pragma unroll
    for (int ni = 0; ni < 2; ni++) a1[mi][ni] = (f32x4){0.f,0.f,0.f,0.f};
  const unsigned short* W0 = w0b + (size_t)b * 4096;
  #pragma unroll
  for (int ks = 0; ks < 2; ks++){
    short8 bfh[2];
    #pragma unroll
    for (int ni = 0; ni < 2; ni++){
      int n = w * 32 + ni * 16 + l15;
      unsigned off = ((unsigned)(n * 128 + ks * 64 + g * 16)) ^ ((unsigned)((n & 7) << 4));
      bfh[ni] = *(const short8*)((unsigned char*)H0 + off);
    }
    #pragma unroll
    for (int mi = 0; mi < 4; mi++){
      short8 af = *(const short8*)(W0 + (mi * 16 + l15) * 64 + ks * 32 + g * 8);
      #pragma unroll
      for (int ni = 0; ni < 2; ni++)
        a1[mi][ni] = __builtin_amdgcn_mfma_f32_16x16x32_bf16(af, bfh[ni], a1[mi][ni], 0, 0, 0);
    }
  }
  const float* pp = params + (size_t)b * 8385;
  const float* b0p = pp + 8256;
  __syncthreads();                            // H0 reads done before H1 write overlap
  #pragma unroll
  for (int mi = 0; mi < 4; mi++)
    #pragma unroll
    for (int ni = 0; ni < 2; ni++){
      int n = w * 32 + ni * 16 + l15;
      unsigned base = ((unsigned)(n * 128 + mi * 32 + g * 8)) ^ ((unsigned)((n & 7) << 4));
      unsigned short hh[4];
      #pragma unroll
      for (int r = 0; r < 4; r++){
        int o = mi * 16 + g * 4 + r;
        hh[r] = f2bf(fmaxf(a1[mi][ni][r] + b0p[o], 0.f));
      }
      *(unsigned*)((unsigned char*)H1 + base)     = (unsigned)hh[0] | ((unsigned)hh[1] << 16);
      *(unsigned*)((unsigned char*)H1 + base + 4) = (unsigned)hh[2] | ((unsigned)hh[3] << 16);
    }
  __syncthreads();
  f32x4 a2[4][2];
  #pragma unroll
  for (int mi = 0; mi < 4; mi++)
    #pragma unroll
    for (int ni = 0; ni < 2; ni++) a2[mi][ni] = (f32x4){0.f,0.f,0.f,0.f};
  const unsigned short* W1 = w1b + (size_t)b * 4096;
  #pragma unroll
  for (int ks = 0; ks < 2; ks++){
    short8 bfh[2];
    #pragma unroll
    for (int ni = 0; ni < 2; ni++){
      int n = w * 32 + ni * 16 + l15;
      unsigned off = ((unsigned)(n * 128 + ks * 64 + g * 16)) ^ ((unsigned)((n & 7) << 4));
      bfh[ni] = *(const short8*)((unsigned char*)H1 + off);
    }
    #pragma unroll
    for (int mi = 0; mi < 4; mi++){
      short8 af = *(const short8*)(W1 + (mi * 16 + l15) * 64 + ks * 32 + g * 8);
      #pragma unroll
      for (int ni = 0; ni < 2; ni++)
        a2[mi][ni] = __builtin_amdgcn_mfma_f32_16x16x32_bf16(af, bfh[ni], a2[mi][ni], 0, 0, 0);
    }
  }
  const float* b1p = pp + 8320;
  const float* w2p = pp + 8192;
  float b2v = pp[8384];
  #pragma unroll
  for (int ni = 0; ni < 2; ni++){
    float t = 0.f;
    #pragma unroll
    for (int mi = 0; mi < 4; mi++)
      #pragma unroll
      for (int r = 0; r < 4; r++){
        int o = mi * 16 + g * 4 + r;
        t += w2p[o] * fmaxf(a2[mi][ni][r] + b1p[o], 0.f);
      }
    t += __shfl_xor(t, 16);
    t += __shfl_xor(t, 32);
    if (lane < 16)
      out[(size_t)b * 16384 + n0 + w * 32 + ni * 16 + l15] = t + b2v;
  }
}

extern "C" void kernel_launch(void* const* d_in, const int* in_sizes, int n_in,
                              void* d_out, int out_size, void* d_ws, size_t ws_size,
                              hipStream_t stream){
  const float* scene = (const float*)d_in[0];
  const float* tmpl  = (const float*)d_in[1];
  const float* qw    = (const float*)d_in[2];
  const float* kw    = (const float*)d_in[3];
  const float* vw    = (const float*)d_in[4];
  const float* pw    = (const float*)d_in[5];
  const float* pb    = (const float*)d_in[6];
  const float* cw    = (const float*)d_in[7];
  const float* cb    = (const float*)d_in[8];
  float* out = (float*)d_out;
  char* ws = (char*)d_ws;

  unsigned short* Q      = (unsigned short*)(ws + 0);                    // 2 MB
  unsigned short* K      = (unsigned short*)(ws + (2u << 20));           // 2 MB
  unsigned char*  V8     = (unsigned char*)(ws + (4u << 20));            // 4 MB
  unsigned*       pooledEnc = (unsigned*)(ws + (12u << 20));             // 8 KB
  unsigned*       tmaxe  = (unsigned*)(ws + (12u << 20) + 8192);         // 8 KB
  float*          params = (float*)(ws + (12u << 20) + 16384);           // 268 KB
  unsigned short* w0b    = (unsigned short*)(ws + (13u << 20));          // 64 KB
  unsigned short* w1b    = (unsigned short*)(ws + (13u << 20) + 65536);  // 64 KB
  unsigned short* weff   = (unsigned short*)(ws + (13u << 20) + 131072); // 256 KB
  float*          beff   = (float*)(ws + (13u << 20) + 131072 + 262144); // 2 KB
  float*          sbuf   = (float*)(ws + (14u << 20));                   // 64 KB
  unsigned short* Wbf    = (unsigned short*)(ws + (14u << 20) + 131072); // 192 KB
  unsigned char*  P8buf  = (unsigned char*)(ws + (16u << 20));           // up to 33.5 MB
  unsigned short* Tt     = (unsigned short*)P8buf;  // 8 MB; dead before kA writes

  const size_t pPerBatch = (size_t)2048 * 2048;     // 4 MB fp8 per batch
  size_t avail = ws_size > (16u << 20) ? ws_size - (16u << 20) : 0;
  int nb = 8, bshift = 3;
  while (nb > 1 && (size_t)nb * pPerBatch > avail){ nb >>= 1; bshift--; }

  hipMemsetAsync(ws + (12u << 20), 0, 16384, stream);   // pooledEnc + tmaxe floors
  k0_tt<<<dim3(1120), dim3(256), 0, stream>>>(tmpl, Tt, pooledEnc, qw, kw, vw, Wbf);
  k23_qkv_params<<<dim3(512 + 2097), dim3(256), 0, stream>>>(Wbf, Tt, Q, K, V8,
                                                             pooledEnc, cw, cb, params);
  for (int b0 = 0; b0 < 8; b0 += nb){
    kA_scores<<<dim3(64 * nb), dim3(512), 0, stream>>>(Q, K, P8buf, sbuf, b0, bshift);
    kB_pv<<<dim3(64 * nb), dim3(256), 0, stream>>>(P8buf, V8, sbuf, tmaxe, b0, bshift);
  }
  k5_weff<<<dim3(64, 8), dim3(256), 0, stream>>>(pw, pb, tmaxe, params, weff, beff, w0b, w1b);
  k6_main<<<dim3(128, 8), dim3(256), 0, stream>>>(scene, weff, beff, w0b, w1b, params, out);
}